// Round 1
// baseline (279.357 us; speedup 1.0000x reference)
//
#include <hip/hip_runtime.h>
#include <math.h>

#define FT 48
#define NPIX (FT * FT)      // 2304
#define CIN 24
#define HC 96
#define NORM_SCALE 0.007843137718737125f
#define OUT_SCALE 0.02083333395421505f
#define DELTA 1.8f

// ---------------- fused head: norm -> dw3x3 -> pw1+relu -> pw2 ----------------

template <int CLS>
__device__ __forceinline__ void run_head(
    const float* __restrict__ x,
    const float* __restrict__ dw_w, const float* __restrict__ dw_b,
    const float* __restrict__ pw1_w, const float* __restrict__ pw1_b,
    const float* __restrict__ pw2_w, const float* __restrict__ pw2_b,
    float* __restrict__ out, int p)
{
    const int py = p / FT;
    const int px = p % FT;

    // depthwise 3x3 (cross-correlation, SAME padding with zeros on the
    // *normalized* input per reference: normalize first, conv pads with 0)
    float dwv[CIN];
#pragma unroll
    for (int ci = 0; ci < CIN; ++ci) {
        float acc = dw_b[ci];
#pragma unroll
        for (int ky = 0; ky < 3; ++ky) {
            const int yy = py + ky - 1;
#pragma unroll
            for (int kx = 0; kx < 3; ++kx) {
                const int xx = px + kx - 1;
                float v = 0.0f;
                if (yy >= 0 && yy < FT && xx >= 0 && xx < FT)
                    v = x[ci * NPIX + yy * FT + xx] * NORM_SCALE - 1.0f;
                acc = fmaf(dw_w[ci * 9 + ky * 3 + kx], v, acc);
            }
        }
        dwv[ci] = acc;
    }

    // pw1 (24->96) + relu, with pw2 (96->CLS) accumulated on the fly
    float oacc[CLS];
#pragma unroll
    for (int k = 0; k < CLS; ++k) oacc[k] = pw2_b[k];

    for (int co = 0; co < HC; ++co) {
        float a = pw1_b[co];
#pragma unroll
        for (int ci = 0; ci < CIN; ++ci)
            a = fmaf(pw1_w[co * CIN + ci], dwv[ci], a);
        a = fmaxf(a, 0.0f);
#pragma unroll
        for (int k = 0; k < CLS; ++k)
            oacc[k] = fmaf(pw2_w[k * HC + co], a, oacc[k]);
    }

#pragma unroll
    for (int k = 0; k < CLS; ++k)
        out[k * NPIX + p] = oacc[k];
}

struct Params {
    const float* x;
    const float* w[4][6];   // per head: dw_w, dw_b, pw1_w, pw1_b, pw2_w, pw2_b
    float* out[4];
};

__global__ __launch_bounds__(256) void heads_kernel(Params p)
{
    const int head = blockIdx.x / 9;
    const int pix = (blockIdx.x % 9) * 256 + threadIdx.x;
    switch (head) {
        case 0: run_head<17>(p.x, p.w[0][0], p.w[0][1], p.w[0][2], p.w[0][3], p.w[0][4], p.w[0][5], p.out[0], pix); break;
        case 1: run_head<1>(p.x, p.w[1][0], p.w[1][1], p.w[1][2], p.w[1][3], p.w[1][4], p.w[1][5], p.out[1], pix); break;
        case 2: run_head<34>(p.x, p.w[2][0], p.w[2][1], p.w[2][2], p.w[2][3], p.w[2][4], p.w[2][5], p.out[2], pix); break;
        default: run_head<34>(p.x, p.w[3][0], p.w[3][1], p.w[3][2], p.w[3][3], p.w[3][4], p.w[3][5], p.out[3], pix); break;
    }
}

// ---------------- decode ----------------

__device__ __forceinline__ float sigmoidf_(float v) { return 1.0f / (1.0f + expf(-v)); }

__global__ __launch_bounds__(256) void decode_kernel(
    const float* __restrict__ hm_hp,   // [17][2304]
    const float* __restrict__ hm,      // [1][2304]
    const float* __restrict__ hps,     // [34][2304]
    const float* __restrict__ hp_off,  // [34][2304]
    float* __restrict__ out)           // [51]
{
    __shared__ float s_val[256];
    __shared__ int s_idx[256];
    __shared__ float s_kcy[17], s_kcx[17];
    __shared__ int s_top[17];
    __shared__ int s_ct;

    const int t = threadIdx.x;

    // ---- phase A: center-weighted argmax over center heatmap ----
    float best = -1e30f;
    int bidx = 0x7fffffff;
    for (int i = t; i < NPIX; i += 256) {
        const int y = i / FT, x = i % FT;
        const float c = sigmoidf_(hm[i]);
        const float gy = (float)y - 24.0f, gx = (float)x - 24.0f;
        const float w = 1.0f / (sqrtf(gy * gy + gx * gx) + DELTA);
        const float v = c * w;
        if (v > best || (v == best && i < bidx)) { best = v; bidx = i; }
    }
    s_val[t] = best;
    s_idx[t] = bidx;
    __syncthreads();
    for (int s = 128; s > 0; s >>= 1) {
        if (t < s) {
            const float v2 = s_val[t + s];
            const int i2 = s_idx[t + s];
            if (v2 > s_val[t] || (v2 == s_val[t] && i2 < s_idx[t])) {
                s_val[t] = v2;
                s_idx[t] = i2;
            }
        }
        __syncthreads();
    }
    if (t == 0) s_ct = s_idx[0];
    __syncthreads();

    const int ct = s_ct;
    const float cty = (float)(ct / FT);
    const float ctx = (float)(ct % FT);

    // ---- phase B: keypoint anchor coords = regress@center + center ----
    if (t < 17) {
        s_kcy[t] = hps[(2 * t) * NPIX + ct] + cty;
        s_kcx[t] = hps[(2 * t + 1) * NPIX + ct] + ctx;
    }
    __syncthreads();

    // ---- phase C: per-keypoint distance-weighted argmax (1 wave / kpt) ----
    const int lane = t & 63;
    const int wv = t >> 6;
    for (int k = wv; k < 17; k += 4) {
        const float kcy = s_kcy[k], kcx = s_kcx[k];
        float b = -1e30f;
        int bi = 0x7fffffff;
        for (int i = lane; i < NPIX; i += 64) {
            const int y = i / FT, x = i % FT;
            const float dy = (float)y - kcy, dx = (float)x - kcx;
            const float d = sqrtf(dy * dy + dx * dx) + DELTA;
            const float v = sigmoidf_(hm_hp[k * NPIX + i]) / d;
            if (v > b || (v == b && i < bi)) { b = v; bi = i; }
        }
        for (int off = 32; off > 0; off >>= 1) {
            const float v2 = __shfl_down(b, off, 64);
            const int i2 = __shfl_down(bi, off, 64);
            if (v2 > b || (v2 == b && i2 < bi)) { b = v2; bi = i2; }
        }
        if (lane == 0) s_top[k] = bi;
    }
    __syncthreads();

    // ---- phase D: gather + write [17][3] = (y, x, conf) ----
    if (t < 17) {
        const int top = s_top[t];
        const int ty = top / FT, tx = top % FT;
        const float conf = sigmoidf_(hm_hp[t * NPIX + top]);
        const float oy = hp_off[(2 * t) * NPIX + top];
        const float ox = hp_off[(2 * t + 1) * NPIX + top];
        out[t * 3 + 0] = (oy + (float)ty) * OUT_SCALE;
        out[t * 3 + 1] = (ox + (float)tx) * OUT_SCALE;
        out[t * 3 + 2] = conf;
    }
}

// ---------------- launch ----------------

extern "C" void kernel_launch(void* const* d_in, const int* in_sizes, int n_in,
                              void* d_out, int out_size, void* d_ws, size_t ws_size,
                              hipStream_t stream)
{
    (void)in_sizes; (void)n_in; (void)out_size; (void)ws_size;

    float* ws = (float*)d_ws;
    float* o_hmhp = ws;                  // 17 * 2304
    float* o_hm   = ws + 17 * NPIX;      //  1 * 2304
    float* o_hps  = ws + 18 * NPIX;      // 34 * 2304
    float* o_hpo  = ws + 52 * NPIX;      // 34 * 2304

    Params p;
    p.x = (const float*)d_in[0];
    for (int h = 0; h < 4; ++h)
        for (int j = 0; j < 6; ++j)
            p.w[h][j] = (const float*)d_in[1 + h * 6 + j];
    p.out[0] = o_hmhp;
    p.out[1] = o_hm;
    p.out[2] = o_hps;
    p.out[3] = o_hpo;

    heads_kernel<<<36, 256, 0, stream>>>(p);
    decode_kernel<<<1, 256, 0, stream>>>(o_hmhp, o_hm, o_hps, o_hpo, (float*)d_out);
}

// Round 2
// 240.905 us; speedup vs baseline: 1.1596x; 1.1596x over previous
//
#include <hip/hip_runtime.h>
#include <math.h>

#define FT 48
#define NPIX (FT * FT)      // 2304
#define CIN 24
#define HC 96
#define NORM_SCALE 0.007843137718737125f
#define OUT_SCALE 0.02083333395421505f
#define DELTA 1.8f

__device__ __forceinline__ float sigmoidf_(float v) { return 1.0f / (1.0f + expf(-v)); }

// depthwise 3x3 on normalized input at pixel p -> dwv[24]
__device__ __forceinline__ void dwconv_at(
    const float* __restrict__ x,
    const float* __restrict__ dw_w, const float* __restrict__ dw_b,
    int p, float* __restrict__ dwv)
{
    const int py = p / FT;
    const int px = p % FT;
#pragma unroll
    for (int ci = 0; ci < CIN; ++ci) {
        float acc = dw_b[ci];
#pragma unroll
        for (int ky = 0; ky < 3; ++ky) {
            const int yy = py + ky - 1;
#pragma unroll
            for (int kx = 0; kx < 3; ++kx) {
                const int xx = px + kx - 1;
                float v = 0.0f;
                if (yy >= 0 && yy < FT && xx >= 0 && xx < FT)
                    v = x[ci * NPIX + yy * FT + xx] * NORM_SCALE - 1.0f;
                acc = fmaf(dw_w[ci * 9 + ky * 3 + kx], v, acc);
            }
        }
        dwv[ci] = acc;
    }
}

// ---------------- kernel 1: hm_hp (full, sigmoided) + hm (partial argmax) ----

struct P1 {
    const float* x;
    const float* hmhp_w[6];   // dw_w, dw_b, pw1_w, pw1_b, pw2_w, pw2_b
    const float* hm_w[6];
    float* hmhp_sig;          // [17][2304]
    float* pval;              // [9]
    int*   pidx;              // [9]
};

__global__ __launch_bounds__(256) void k1_heads(P1 p)
{
    __shared__ float s_val[256];
    __shared__ int s_idx[256];

    const int b = blockIdx.x;
    const int t = threadIdx.x;

    if (b < 9) {
        // ---- hm_hp head, CLS=17 ----
        const int pix = b * 256 + t;
        float dwv[CIN];
        dwconv_at(p.x, p.hmhp_w[0], p.hmhp_w[1], pix, dwv);

        const float* pw1_w = p.hmhp_w[2];
        const float* pw1_b = p.hmhp_w[3];
        const float* pw2_w = p.hmhp_w[4];
        const float* pw2_b = p.hmhp_w[5];

        float oacc[17];
#pragma unroll
        for (int k = 0; k < 17; ++k) oacc[k] = pw2_b[k];

#pragma unroll 8
        for (int co = 0; co < HC; ++co) {
            float a = pw1_b[co];
#pragma unroll
            for (int ci = 0; ci < CIN; ++ci)
                a = fmaf(pw1_w[co * CIN + ci], dwv[ci], a);
            a = fmaxf(a, 0.0f);
#pragma unroll
            for (int k = 0; k < 17; ++k)
                oacc[k] = fmaf(pw2_w[k * HC + co], a, oacc[k]);
        }

#pragma unroll
        for (int k = 0; k < 17; ++k)
            p.hmhp_sig[k * NPIX + pix] = sigmoidf_(oacc[k]);
    } else {
        // ---- hm head, CLS=1, fused center-weighted partial argmax ----
        const int lb = b - 9;
        const int pix = lb * 256 + t;
        float dwv[CIN];
        dwconv_at(p.x, p.hm_w[0], p.hm_w[1], pix, dwv);

        const float* pw1_w = p.hm_w[2];
        const float* pw1_b = p.hm_w[3];
        const float* pw2_w = p.hm_w[4];
        const float* pw2_b = p.hm_w[5];

        float o = pw2_b[0];
#pragma unroll 8
        for (int co = 0; co < HC; ++co) {
            float a = pw1_b[co];
#pragma unroll
            for (int ci = 0; ci < CIN; ++ci)
                a = fmaf(pw1_w[co * CIN + ci], dwv[ci], a);
            a = fmaxf(a, 0.0f);
            o = fmaf(pw2_w[co], a, o);
        }

        const int y = pix / FT, xx = pix % FT;
        const float gy = (float)y - 24.0f, gx = (float)xx - 24.0f;
        const float w = 1.0f / (sqrtf(gy * gy + gx * gx) + DELTA);
        const float v = sigmoidf_(o) * w;

        s_val[t] = v;
        s_idx[t] = pix;
        __syncthreads();
        for (int s = 128; s > 0; s >>= 1) {
            if (t < s) {
                const float v2 = s_val[t + s];
                const int i2 = s_idx[t + s];
                if (v2 > s_val[t] || (v2 == s_val[t] && i2 < s_idx[t])) {
                    s_val[t] = v2;
                    s_idx[t] = i2;
                }
            }
            __syncthreads();
        }
        if (t == 0) { p.pval[lb] = s_val[0]; p.pidx[lb] = s_idx[0]; }
    }
}

// ---------------- kernel 2: per-keypoint decode (17 blocks) ----------------

struct P2 {
    const float* x;
    const float* hps_w[6];
    const float* hpo_w[6];
    const float* hmhp_sig;
    const float* pval;
    const int*   pidx;
    float* out;
};

__global__ __launch_bounds__(256) void k2_decode(P2 p)
{
    __shared__ float s_v[256];
    __shared__ int s_i[256];
    __shared__ float sA[HC];
    __shared__ float s_ky, s_kx;
    __shared__ int s_ct, s_top;

    const int k = blockIdx.x;
    const int t = threadIdx.x;

    // ---- finalize center argmax from 9 partials ----
    if (t == 0) {
        float bv = -1e30f;
        int bi = 0x7fffffff;
        for (int b = 0; b < 9; ++b) {
            const float v = p.pval[b];
            const int i = p.pidx[b];
            if (v > bv || (v == bv && i < bi)) { bv = v; bi = i; }
        }
        s_ct = bi;
    }
    __syncthreads();
    const int ct = s_ct;
    const float cty = (float)(ct / FT);
    const float ctx = (float)(ct % FT);

    // ---- hps channels 2k, 2k+1 at pixel ct ----
    if (t < HC) {
        float dwv[CIN];
        dwconv_at(p.x, p.hps_w[0], p.hps_w[1], ct, dwv);
        float a = p.hps_w[3][t];
#pragma unroll
        for (int ci = 0; ci < CIN; ++ci)
            a = fmaf(p.hps_w[2][t * CIN + ci], dwv[ci], a);
        sA[t] = fmaxf(a, 0.0f);
    }
    __syncthreads();
    if (t == 0) {
        const float* pw2_w = p.hps_w[4];
        const float* pw2_b = p.hps_w[5];
        float vy = pw2_b[2 * k], vx = pw2_b[2 * k + 1];
        for (int co = 0; co < HC; ++co) {
            vy = fmaf(pw2_w[(2 * k) * HC + co], sA[co], vy);
            vx = fmaf(pw2_w[(2 * k + 1) * HC + co], sA[co], vx);
        }
        s_ky = vy + cty;
        s_kx = vx + ctx;
    }
    __syncthreads();
    const float kcy = s_ky, kcx = s_kx;

    // ---- distance-weighted argmax over hm_hp[k] ----
    float best = -1e30f;
    int bi = 0x7fffffff;
    for (int i = t; i < NPIX; i += 256) {
        const int y = i / FT, xx = i % FT;
        const float dy = (float)y - kcy, dx = (float)xx - kcx;
        const float d = sqrtf(dy * dy + dx * dx) + DELTA;
        const float v = p.hmhp_sig[k * NPIX + i] / d;
        if (v > best || (v == best && i < bi)) { best = v; bi = i; }
    }
    s_v[t] = best;
    s_i[t] = bi;
    __syncthreads();
    for (int s = 128; s > 0; s >>= 1) {
        if (t < s) {
            const float v2 = s_v[t + s];
            const int i2 = s_i[t + s];
            if (v2 > s_v[t] || (v2 == s_v[t] && i2 < s_i[t])) {
                s_v[t] = v2;
                s_i[t] = i2;
            }
        }
        __syncthreads();
    }
    if (t == 0) s_top = s_i[0];
    __syncthreads();
    const int top = s_top;

    // ---- hp_offset channels 2k, 2k+1 at pixel top ----
    if (t < HC) {
        float dwv[CIN];
        dwconv_at(p.x, p.hpo_w[0], p.hpo_w[1], top, dwv);
        float a = p.hpo_w[3][t];
#pragma unroll
        for (int ci = 0; ci < CIN; ++ci)
            a = fmaf(p.hpo_w[2][t * CIN + ci], dwv[ci], a);
        sA[t] = fmaxf(a, 0.0f);
    }
    __syncthreads();
    if (t == 0) {
        const float* pw2_w = p.hpo_w[4];
        const float* pw2_b = p.hpo_w[5];
        float oy = pw2_b[2 * k], ox = pw2_b[2 * k + 1];
        for (int co = 0; co < HC; ++co) {
            oy = fmaf(pw2_w[(2 * k) * HC + co], sA[co], oy);
            ox = fmaf(pw2_w[(2 * k + 1) * HC + co], sA[co], ox);
        }
        const float ty = (float)(top / FT), tx = (float)(top % FT);
        p.out[k * 3 + 0] = (oy + ty) * OUT_SCALE;
        p.out[k * 3 + 1] = (ox + tx) * OUT_SCALE;
        p.out[k * 3 + 2] = p.hmhp_sig[k * NPIX + top];
    }
}

// ---------------- launch ----------------

extern "C" void kernel_launch(void* const* d_in, const int* in_sizes, int n_in,
                              void* d_out, int out_size, void* d_ws, size_t ws_size,
                              hipStream_t stream)
{
    (void)in_sizes; (void)n_in; (void)out_size; (void)ws_size;

    float* ws = (float*)d_ws;
    float* hmhp_sig = ws;                    // 17 * 2304
    float* pval     = ws + 17 * NPIX;        // 9
    int*   pidx     = (int*)(ws + 17 * NPIX + 9);

    // input order: x, then per head (hm_hp, hm, hps, hp_offset):
    //   dw_w, dw_b, pw1_w, pw1_b, pw2_w, pw2_b
    P1 p1;
    p1.x = (const float*)d_in[0];
    for (int j = 0; j < 6; ++j) p1.hmhp_w[j] = (const float*)d_in[1 + j];
    for (int j = 0; j < 6; ++j) p1.hm_w[j]   = (const float*)d_in[7 + j];
    p1.hmhp_sig = hmhp_sig;
    p1.pval = pval;
    p1.pidx = pidx;

    P2 p2;
    p2.x = (const float*)d_in[0];
    for (int j = 0; j < 6; ++j) p2.hps_w[j] = (const float*)d_in[13 + j];
    for (int j = 0; j < 6; ++j) p2.hpo_w[j] = (const float*)d_in[19 + j];
    p2.hmhp_sig = hmhp_sig;
    p2.pval = pval;
    p2.pidx = pidx;
    p2.out = (float*)d_out;

    k1_heads<<<18, 256, 0, stream>>>(p1);
    k2_decode<<<17, 256, 0, stream>>>(p2);
}

// Round 3
// 126.689 us; speedup vs baseline: 2.2051x; 1.9015x over previous
//
#include <hip/hip_runtime.h>
#include <math.h>

#define FT 48
#define NPIX (FT * FT)      // 2304
#define CIN 24
#define HC 96
#define NORM_SCALE 0.007843137718737125f
#define OUT_SCALE 0.02083333395421505f
#define DELTA 1.8f

__device__ __forceinline__ float sigmoidf_(float v) { return 1.0f / (1.0f + expf(-v)); }

// ============================================================================
// kernel 1: 144 blocks x 256 threads.
//   blocks 0..71 : hm_hp head (17 ch), 32 pixels/block, 8 lanes cooperate/pixel
//   blocks 72..143: hm head (1 ch) + center-weighted partial argmax per block
// Lane layout within a wave: pixel group = lane>>3 (8 pixels/wave),
// split = lane&7 (8 co-slices of 12 each; 3 dw-channels each, shared by shfl).
// ============================================================================

struct P1 {
    const float* x;
    const float* hmhp_w[6];   // dw_w, dw_b, pw1_w, pw1_b, pw2_w, pw2_b
    const float* hm_w[6];
    float* hmhp_sig;          // [17][2304] sigmoided
    float* pval;              // [72]
    int*   pidx;              // [72]
};

__global__ __launch_bounds__(256) void k1_heads(P1 p)
{
    __shared__ float sv[4];
    __shared__ int si[4];

    const int t = threadIdx.x;
    const int lane = t & 63;
    const int split = lane & 7;
    const int b = blockIdx.x;
    const bool is_hm = (b >= 72);
    const int lb = is_hm ? b - 72 : b;
    const int pix = lb * 32 + (t >> 3);
    const int py = pix / FT;
    const int px = pix % FT;

    const float* dw_w  = is_hm ? p.hm_w[0] : p.hmhp_w[0];
    const float* dw_b  = is_hm ? p.hm_w[1] : p.hmhp_w[1];
    const float* pw1_w = is_hm ? p.hm_w[2] : p.hmhp_w[2];
    const float* pw1_b = is_hm ? p.hm_w[3] : p.hmhp_w[3];
    const float* pw2_w = is_hm ? p.hm_w[4] : p.hmhp_w[4];
    const float* pw2_b = is_hm ? p.hm_w[5] : p.hmhp_w[5];

    // ---- depthwise: this lane computes dw channels 3*split .. 3*split+2 ----
    float part[3];
#pragma unroll
    for (int c = 0; c < 3; ++c) {
        const int ci = split * 3 + c;
        float acc = dw_b[ci];
#pragma unroll
        for (int ky = 0; ky < 3; ++ky) {
            const int yy = py + ky - 1;
#pragma unroll
            for (int kx = 0; kx < 3; ++kx) {
                const int xx = px + kx - 1;
                float v = 0.0f;
                if (yy >= 0 && yy < FT && xx >= 0 && xx < FT)
                    v = p.x[ci * NPIX + yy * FT + xx] * NORM_SCALE - 1.0f;
                acc = fmaf(dw_w[ci * 9 + ky * 3 + kx], v, acc);
            }
        }
        part[c] = acc;
    }

    // ---- share dwv[24] across the 8-lane group via shuffles ----
    float dwv[CIN];
    const int gbase = lane & ~7;
#pragma unroll
    for (int ci = 0; ci < CIN; ++ci) {
        const float v = (ci % 3 == 0) ? part[0] : ((ci % 3 == 1) ? part[1] : part[2]);
        dwv[ci] = __shfl(v, gbase | (ci / 3), 64);
    }

    if (!is_hm) {
        // -------- hm_hp: 17 outputs --------
        float oacc[17];
#pragma unroll
        for (int k = 0; k < 17; ++k) oacc[k] = 0.0f;

#pragma unroll 4
        for (int j = 0; j < 12; ++j) {
            const int co = j * 8 + split;
            float a = pw1_b[co];
#pragma unroll
            for (int ci = 0; ci < CIN; ++ci)
                a = fmaf(pw1_w[co * CIN + ci], dwv[ci], a);
            a = fmaxf(a, 0.0f);
#pragma unroll
            for (int k = 0; k < 17; ++k)
                oacc[k] = fmaf(pw2_w[k * HC + co], a, oacc[k]);
        }
        // reduce across the 8 splits
#pragma unroll
        for (int off = 1; off < 8; off <<= 1)
#pragma unroll
            for (int k = 0; k < 17; ++k)
                oacc[k] += __shfl_xor(oacc[k], off, 64);
        // write: lane 'split' writes k = split, split+8, (split==0: 16)
        {
            int k = split;
            p.hmhp_sig[k * NPIX + pix] = sigmoidf_(oacc[k] + pw2_b[k]);
            k = split + 8;
            p.hmhp_sig[k * NPIX + pix] = sigmoidf_(oacc[k] + pw2_b[k]);
            if (split == 0)
                p.hmhp_sig[16 * NPIX + pix] = sigmoidf_(oacc[16] + pw2_b[16]);
        }
    } else {
        // -------- hm: 1 output + center-weighted partial argmax --------
        float acc1 = 0.0f;
#pragma unroll 4
        for (int j = 0; j < 12; ++j) {
            const int co = j * 8 + split;
            float a = pw1_b[co];
#pragma unroll
            for (int ci = 0; ci < CIN; ++ci)
                a = fmaf(pw1_w[co * CIN + ci], dwv[ci], a);
            a = fmaxf(a, 0.0f);
            acc1 = fmaf(pw2_w[co], a, acc1);
        }
#pragma unroll
        for (int off = 1; off < 8; off <<= 1)
            acc1 += __shfl_xor(acc1, off, 64);

        float v = -1e30f;
        int idx = pix;
        if (split == 0) {
            const float o = acc1 + pw2_b[0];
            const float gy = (float)py - 24.0f, gx = (float)px - 24.0f;
            const float w = 1.0f / (sqrtf(gy * gy + gx * gx) + DELTA);
            v = sigmoidf_(o) * w;
        }
        // 64-lane argmax butterfly (tie -> smaller idx)
#pragma unroll
        for (int off = 1; off < 64; off <<= 1) {
            const float v2 = __shfl_xor(v, off, 64);
            const int i2 = __shfl_xor(idx, off, 64);
            if (v2 > v || (v2 == v && i2 < idx)) { v = v2; idx = i2; }
        }
        if (lane == 0) { sv[t >> 6] = v; si[t >> 6] = idx; }
        __syncthreads();
        if (t == 0) {
            float bv = sv[0]; int bi = si[0];
#pragma unroll
            for (int w2 = 1; w2 < 4; ++w2)
                if (sv[w2] > bv || (sv[w2] == bv && si[w2] < bi)) { bv = sv[w2]; bi = si[w2]; }
            p.pval[lb] = bv;
            p.pidx[lb] = bi;
        }
    }
}

// ============================================================================
// kernel 2: 17 blocks x 256 threads, one block per keypoint.
// ============================================================================

struct P2 {
    const float* x;
    const float* hps_w[6];
    const float* hpo_w[6];
    const float* hmhp_sig;
    const float* pval;
    const int*   pidx;
    float* out;
};

__device__ __forceinline__ float dw_tap(const float* __restrict__ x,
                                        const float* __restrict__ dw_w,
                                        const float* __restrict__ dw_b,
                                        int ci, int pixel)
{
    const int py = pixel / FT, px = pixel % FT;
    float acc = dw_b[ci];
#pragma unroll
    for (int ky = 0; ky < 3; ++ky) {
        const int yy = py + ky - 1;
#pragma unroll
        for (int kx = 0; kx < 3; ++kx) {
            const int xx = px + kx - 1;
            float v = 0.0f;
            if (yy >= 0 && yy < FT && xx >= 0 && xx < FT)
                v = x[ci * NPIX + yy * FT + xx] * NORM_SCALE - 1.0f;
            acc = fmaf(dw_w[ci * 9 + ky * 3 + kx], v, acc);
        }
    }
    return acc;
}

__global__ __launch_bounds__(256) void k2_decode(P2 p)
{
    __shared__ float s_red[256];
    __shared__ int s_redi[256];
    __shared__ float s_dwv[CIN];
    __shared__ float sA[HC];
    __shared__ float s_ky, s_kx;
    __shared__ int s_ct, s_top;

    const int t = threadIdx.x;
    const int k = blockIdx.x;

    // ---- finalize center argmax from 72 partials (parallel loads + tree) ----
    if (t < 128) {
        float v = -1e30f;
        int i = 0x7fffffff;
        if (t < 72) { v = p.pval[t]; i = p.pidx[t]; }
        s_red[t] = v;
        s_redi[t] = i;
    }
    __syncthreads();
    for (int s = 64; s > 0; s >>= 1) {
        if (t < s) {
            const float v2 = s_red[t + s];
            const int i2 = s_redi[t + s];
            if (v2 > s_red[t] || (v2 == s_red[t] && i2 < s_redi[t])) {
                s_red[t] = v2;
                s_redi[t] = i2;
            }
        }
        __syncthreads();
    }
    if (t == 0) s_ct = s_redi[0];
    __syncthreads();
    const int ct = s_ct;
    const float cty = (float)(ct / FT);
    const float ctx = (float)(ct % FT);

    // ---- hps @ ct: dwconv split 24 ways, pw1 split 96 ways ----
    if (t < CIN) s_dwv[t] = dw_tap(p.x, p.hps_w[0], p.hps_w[1], t, ct);
    __syncthreads();
    if (t < HC) {
        float a = p.hps_w[3][t];
#pragma unroll
        for (int ci = 0; ci < CIN; ++ci)
            a = fmaf(p.hps_w[2][t * CIN + ci], s_dwv[ci], a);
        sA[t] = fmaxf(a, 0.0f);
    }
    __syncthreads();
    if (t < 64) {
        float vy = 0.0f, vx = 0.0f;
        for (int co = t; co < HC; co += 64) {
            const float av = sA[co];
            vy = fmaf(p.hps_w[4][(2 * k) * HC + co], av, vy);
            vx = fmaf(p.hps_w[4][(2 * k + 1) * HC + co], av, vx);
        }
#pragma unroll
        for (int off = 1; off < 64; off <<= 1) {
            vy += __shfl_xor(vy, off, 64);
            vx += __shfl_xor(vx, off, 64);
        }
        if (t == 0) {
            s_ky = vy + p.hps_w[5][2 * k] + cty;
            s_kx = vx + p.hps_w[5][2 * k + 1] + ctx;
        }
    }
    __syncthreads();
    const float kcy = s_ky, kcx = s_kx;

    // ---- distance-weighted argmax over hmhp_sig[k] ----
    float best = -1e30f;
    int bi = 0x7fffffff;
    for (int i = t; i < NPIX; i += 256) {
        const int y = i / FT, xx = i % FT;
        const float dy = (float)y - kcy, dx = (float)xx - kcx;
        const float d = sqrtf(dy * dy + dx * dx) + DELTA;
        const float v = p.hmhp_sig[k * NPIX + i] / d;
        if (v > best || (v == best && i < bi)) { best = v; bi = i; }
    }
    s_red[t] = best;
    s_redi[t] = bi;
    __syncthreads();
    for (int s = 128; s > 0; s >>= 1) {
        if (t < s) {
            const float v2 = s_red[t + s];
            const int i2 = s_redi[t + s];
            if (v2 > s_red[t] || (v2 == s_red[t] && i2 < s_redi[t])) {
                s_red[t] = v2;
                s_redi[t] = i2;
            }
        }
        __syncthreads();
    }
    if (t == 0) s_top = s_redi[0];
    __syncthreads();
    const int top = s_top;

    // ---- hp_offset @ top ----
    if (t < CIN) s_dwv[t] = dw_tap(p.x, p.hpo_w[0], p.hpo_w[1], t, top);
    __syncthreads();
    if (t < HC) {
        float a = p.hpo_w[3][t];
#pragma unroll
        for (int ci = 0; ci < CIN; ++ci)
            a = fmaf(p.hpo_w[2][t * CIN + ci], s_dwv[ci], a);
        sA[t] = fmaxf(a, 0.0f);
    }
    __syncthreads();
    if (t < 64) {
        float oy = 0.0f, ox = 0.0f;
        for (int co = t; co < HC; co += 64) {
            const float av = sA[co];
            oy = fmaf(p.hpo_w[4][(2 * k) * HC + co], av, oy);
            ox = fmaf(p.hpo_w[4][(2 * k + 1) * HC + co], av, ox);
        }
#pragma unroll
        for (int off = 1; off < 64; off <<= 1) {
            oy += __shfl_xor(oy, off, 64);
            ox += __shfl_xor(ox, off, 64);
        }
        if (t == 0) {
            const float ty = (float)(top / FT), tx = (float)(top % FT);
            p.out[k * 3 + 0] = (oy + p.hpo_w[5][2 * k] + ty) * OUT_SCALE;
            p.out[k * 3 + 1] = (ox + p.hpo_w[5][2 * k + 1] + tx) * OUT_SCALE;
            p.out[k * 3 + 2] = p.hmhp_sig[k * NPIX + top];
        }
    }
}

// ---------------- launch ----------------

extern "C" void kernel_launch(void* const* d_in, const int* in_sizes, int n_in,
                              void* d_out, int out_size, void* d_ws, size_t ws_size,
                              hipStream_t stream)
{
    (void)in_sizes; (void)n_in; (void)out_size; (void)ws_size;

    float* ws = (float*)d_ws;
    float* hmhp_sig = ws;                     // 17 * 2304
    float* pval     = ws + 17 * NPIX;         // 72
    int*   pidx     = (int*)(ws + 17 * NPIX + 72);

    P1 p1;
    p1.x = (const float*)d_in[0];
    for (int j = 0; j < 6; ++j) p1.hmhp_w[j] = (const float*)d_in[1 + j];
    for (int j = 0; j < 6; ++j) p1.hm_w[j]   = (const float*)d_in[7 + j];
    p1.hmhp_sig = hmhp_sig;
    p1.pval = pval;
    p1.pidx = pidx;

    P2 p2;
    p2.x = (const float*)d_in[0];
    for (int j = 0; j < 6; ++j) p2.hps_w[j] = (const float*)d_in[13 + j];
    for (int j = 0; j < 6; ++j) p2.hpo_w[j] = (const float*)d_in[19 + j];
    p2.hmhp_sig = hmhp_sig;
    p2.pval = pval;
    p2.pidx = pidx;
    p2.out = (float*)d_out;

    k1_heads<<<144, 256, 0, stream>>>(p1);
    k2_decode<<<17, 256, 0, stream>>>(p2);
}